// Round 11
// baseline (253.784 us; speedup 1.0000x reference)
//
#include <hip/hip_runtime.h>

// Deformable conv2d N=8 C=256 H=W=64 Cout=256 3x3 s1 p1 d1 g1 dg1, fp32 I/O.
// fp16-MFMA implicit GEMM, v4:
//  - 512-thread blocks (8 waves = 4 co-groups x 2 pixel-halves) -> 16 waves/CU.
//  - Gathers issued TWO chunks ahead (full-iteration latency window).
//  - XCD-local images: n = bx&7 (round-robin dispatch -> each XCD owns one
//    image's 2.1MB xt slice in its L2).
//  - 8 lanes share each 64B corner line (8B/lane gathers).
//  - preps fused into one launch.

#define H 64
#define W 64
#define CIN 256
#define COUT 256
#define NIMG 8
#define KTAPS 9
#define CK (CIN * KTAPS)  // 2304
#define NCHUNK 72

typedef _Float16 f16;
typedef __attribute__((ext_vector_type(4))) _Float16 f16x4;
typedef __attribute__((ext_vector_type(8))) _Float16 f16x8;
typedef __attribute__((ext_vector_type(4))) float f32x4;

// ---------------- fused prep: x -> fp16 NHWC, w -> fp16 tap-major ----------------
__global__ __launch_bounds__(256) void dcn_prep(const float* __restrict__ x,
                                                const float* __restrict__ w,
                                                f16* __restrict__ xt,
                                                f16* __restrict__ wt) {
    __shared__ f16 tl[64][66];
    __shared__ f16 tw[CK];
    const int b = blockIdx.x;
    const int t = threadIdx.x;
    if (b < 2048) {  // ---- xprep: 8 n x 64 pb x 4 cb ----
        const int n = b >> 8, pb = (b >> 2) & 63, cb = b & 3;
        const float* xn = x + (size_t)(n * CIN + cb * 64) * (H * W) + pb * 64;
        const int c = t >> 4;
        const int p4 = (t & 15) * 4;
#pragma unroll
        for (int pass = 0; pass < 4; ++pass) {
            float4 v = *(const float4*)(xn + (size_t)(c + pass * 16) * (H * W) + p4);
            const int cc = c + pass * 16;
            tl[p4 + 0][cc] = (f16)v.x;
            tl[p4 + 1][cc] = (f16)v.y;
            tl[p4 + 2][cc] = (f16)v.z;
            tl[p4 + 3][cc] = (f16)v.w;
        }
        __syncthreads();
        const int p = t >> 2, cq = (t & 3) * 16;
        f16* dst = xt + (size_t)n * (H * W) * CIN + (size_t)(pb * 64 + p) * CIN + cb * 64 + cq;
        *(f16x8*)dst = *(const f16x8*)&tl[p][cq];
        *(f16x8*)(dst + 8) = *(const f16x8*)&tl[p][cq + 8];
    } else {  // ---- wprep: one co row per block ----
        const int co = b - 2048;
        const float* wr = w + (size_t)co * CK + t * 9;
        float v[9];
#pragma unroll
        for (int j = 0; j < 9; ++j) v[j] = wr[j];
#pragma unroll
        for (int j = 0; j < 9; ++j) tw[j * 256 + t] = (f16)v[j];  // [tap][c]
        __syncthreads();
        f16* o = wt + (size_t)co * CK;
        for (int i = t; i < CK / 8; i += 256)
            *(f16x8*)(o + i * 8) = *(const f16x8*)(tw + i * 8);
    }
}

// ---------------- main fp16-MFMA kernel (512 threads, deep pipeline) ----------------
__global__ __launch_bounds__(512, 4) void dcn_mfma(
    const f16* __restrict__ xt, const float* __restrict__ offset,
    const f16* __restrict__ wt, const float* __restrict__ bias,
    float* __restrict__ out) {
    __shared__ int s_pix[4][KTAPS][64];  // corner row byte offsets   9216 B
    __shared__ f16 s_wbh[4][KTAPS][64];  // bilinear weights (f16)    4608 B
    __shared__ f16 s_cols[2][64][40];    // double-buffered cols     10240 B

    const int tid = threadIdx.x;
    const int bx = blockIdx.x;
    const int n = bx & 7;       // XCD-local image (round-robin dispatch)
    const int t_img = bx >> 3;  // 64 tiles of 8x8
    const int tile_y = (t_img >> 3) << 3, tile_x = (t_img & 7) << 3;

    // ---- sampling table: 9 taps x 64 pixels ----
    const float* offn = offset + (size_t)n * 18 * (H * W);
    for (int e = tid; e < KTAPS * 64; e += 512) {
        int k = e >> 6, p = e & 63;
        int oy = tile_y + (p >> 3), ox = tile_x + (p & 7);
        float offy = offn[(k * 2 + 0) * (H * W) + oy * W + ox];
        float offx = offn[(k * 2 + 1) * (H * W) + oy * W + ox];
        float py = (float)(oy - 1 + (k / 3)) + offy;
        float px = (float)(ox - 1 + (k % 3)) + offx;
        float y0f = floorf(py), x0f = floorf(px);
        int y0 = (int)y0f, x0 = (int)x0f, y1 = y0 + 1, x1 = x0 + 1;
        float ly = py - y0f, lx = px - x0f, hy = 1.f - ly, hx = 1.f - lx;
        bool vy0 = (y0 >= 0) && (y0 < H), vy1 = (y1 >= 0) && (y1 < H);
        bool vx0 = (x0 >= 0) && (x0 < W), vx1 = (x1 >= 0) && (x1 < W);
        int cy0 = min(max(y0, 0), H - 1), cx0 = min(max(x0, 0), W - 1);
        int cy1 = min(max(y1, 0), H - 1), cx1 = min(max(x1, 0), W - 1);
        s_pix[0][k][p] = (cy0 * W + cx0) * (CIN * 2);
        s_pix[1][k][p] = (cy0 * W + cx1) * (CIN * 2);
        s_pix[2][k][p] = (cy1 * W + cx0) * (CIN * 2);
        s_pix[3][k][p] = (cy1 * W + cx1) * (CIN * 2);
        s_wbh[0][k][p] = (f16)((vy0 && vx0) ? hy * hx : 0.f);
        s_wbh[1][k][p] = (f16)((vy0 && vx1) ? hy * lx : 0.f);
        s_wbh[2][k][p] = (f16)((vy1 && vx0) ? ly * hx : 0.f);
        s_wbh[3][k][p] = (f16)((vy1 && vx1) ? ly * lx : 0.f);
    }

    f32x4 acc[4][2];
#pragma unroll
    for (int i = 0; i < 4; ++i)
#pragma unroll
        for (int j = 0; j < 2; ++j) acc[i][j] = (f32x4)0.f;

    const int lane = tid & 63, wv = tid >> 6;
    const int wvco = wv & 3, hp = wv >> 2;  // co-group, pixel-half
    const int co_base = wvco * 64;
    const int pxbase = hp * 32;

    // gather roles: 8 lanes per pixel, 8B per lane (one 64B line per pixel)
    const int pix_g = tid >> 3;        // 0..63
    const int poff = (tid & 7) * 8;    // byte slot within 64B slice
    const char* xb = (const char*)(xt + (size_t)n * (H * W) * CIN);

    // A-row pointers (vary only by k0)
    const f16* arow[4];
#pragma unroll
    for (int cf = 0; cf < 4; ++cf)
        arow[cf] = wt + (size_t)(co_base + 16 * cf + (lane & 15)) * CK + (lane >> 4) * 8;

    __syncthreads();  // tables ready

    // ---- prologue ----
    // chunk 0: gather + combine + write buf0 (latency exposed once)
    {
        const char* base = xb + poff;  // tap 0, c2 = 0
        f16x4 g0 = *(const f16x4*)(base + s_pix[0][0][pix_g]);
        f16x4 g1 = *(const f16x4*)(base + s_pix[1][0][pix_g]);
        f16x4 g2 = *(const f16x4*)(base + s_pix[2][0][pix_g]);
        f16x4 g3 = *(const f16x4*)(base + s_pix[3][0][pix_g]);
        f16x4 v = g0 * s_wbh[0][0][pix_g] + g1 * s_wbh[1][0][pix_g] +
                  g2 * s_wbh[2][0][pix_g] + g3 * s_wbh[3][0][pix_g];
        *(f16x4*)((char*)&s_cols[0][pix_g][0] + poff) = v;
    }
    // issue gathers for chunk 1 (consumed in iter 0's combine)
    f16x4 hb0, hb1, hb2, hb3;
    {
        const char* base = xb + 64 + poff;  // chunk 1: tap 0, c2 = 64
        hb0 = *(const f16x4*)(base + s_pix[0][0][pix_g]);
        hb1 = *(const f16x4*)(base + s_pix[1][0][pix_g]);
        hb2 = *(const f16x4*)(base + s_pix[2][0][pix_g]);
        hb3 = *(const f16x4*)(base + s_pix[3][0][pix_g]);
    }
    // A-frags chunk 0
    f16x8 af[4];
#pragma unroll
    for (int cf = 0; cf < 4; ++cf) af[cf] = *(const f16x8*)(arow[cf]);
    __syncthreads();

    // ---- main loop: gathers 2 ahead, A-frags 1 ahead, 1 barrier/chunk ----
    for (int cc = 0; cc < NCHUNK; ++cc) {
        const int cur = cc & 1;
        const int c1 = cc + 1, c2i = cc + 2;
        // 1. combine chunk c1 (gathers issued 1 iter ago) -> buf[cur^1]
        if (c1 < NCHUNK) {
            const int tap1 = c1 >> 3;
            f16x4 v = hb0 * s_wbh[0][tap1][pix_g] + hb1 * s_wbh[1][tap1][pix_g] +
                      hb2 * s_wbh[2][tap1][pix_g] + hb3 * s_wbh[3][tap1][pix_g];
            *(f16x4*)((char*)&s_cols[cur ^ 1][pix_g][0] + poff) = v;
        }
        // 2. issue gathers chunk c2i (consumed next iter)
        if (c2i < NCHUNK) {
            const int tap2 = c2i >> 3;
            const char* base = xb + (c2i & 7) * 64 + poff;
            hb0 = *(const f16x4*)(base + s_pix[0][tap2][pix_g]);
            hb1 = *(const f16x4*)(base + s_pix[1][tap2][pix_g]);
            hb2 = *(const f16x4*)(base + s_pix[2][tap2][pix_g]);
            hb3 = *(const f16x4*)(base + s_pix[3][tap2][pix_g]);
        }
        // 3. A-frags chunk c1
        f16x8 afn[4];
        if (c1 < NCHUNK) {
            const int k0 = c1 * 32;
#pragma unroll
            for (int cf = 0; cf < 4; ++cf) afn[cf] = *(const f16x8*)(arow[cf] + k0);
        }
        // 4. B-frags + 8 MFMA
        f16x8 bf[2];
#pragma unroll
        for (int pf = 0; pf < 2; ++pf)
            bf[pf] = *(const f16x8*)&s_cols[cur][pxbase + 16 * pf + (lane & 15)][(lane >> 4) * 8];
#pragma unroll
        for (int cf = 0; cf < 4; ++cf)
#pragma unroll
            for (int pf = 0; pf < 2; ++pf)
                acc[cf][pf] =
                    __builtin_amdgcn_mfma_f32_16x16x32_f16(af[cf], bf[pf], acc[cf][pf], 0, 0, 0);
        if (c1 < NCHUNK) {
#pragma unroll
            for (int cf = 0; cf < 4; ++cf) af[cf] = afn[cf];
        }
        __syncthreads();
    }

    // ---- epilogue: col=lane&15 (pixel), row=(lane>>4)*4+r (co) ----
    float* outn = out + (size_t)n * COUT * (H * W);
#pragma unroll
    for (int cf = 0; cf < 4; ++cf) {
#pragma unroll
        for (int r = 0; r < 4; ++r) {
            int co = co_base + 16 * cf + ((lane >> 4) << 2) + r;
            float b = bias[co];
#pragma unroll
            for (int pf = 0; pf < 2; ++pf) {
                int pp = pxbase + 16 * pf + (lane & 15);
                int oy = tile_y + (pp >> 3), ox = tile_x + (pp & 7);
                outn[(size_t)co * (H * W) + oy * W + ox] = acc[cf][pf][r] + b;
            }
        }
    }
}

// ---------------- fallback fp32 path (ws too small) ----------------
__global__ __launch_bounds__(256) void dcn_transpose_w(const float* __restrict__ w,
                                                       float* __restrict__ wt) {
    __shared__ float tile[32][33];
    const int ckb = blockIdx.x * 32;
    const int cob = blockIdx.y * 32;
    const int tx = threadIdx.x & 31;
    const int ty = threadIdx.x >> 5;
#pragma unroll
    for (int i = 0; i < 32; i += 8)
        tile[ty + i][tx] = w[(size_t)(cob + ty + i) * CK + ckb + tx];
    __syncthreads();
#pragma unroll
    for (int i = 0; i < 32; i += 8)
        wt[(size_t)(ckb + ty + i) * COUT + cob + tx] = tile[tx][ty + i];
}

__global__ __launch_bounds__(256, 2) void dcn_main(
    const float* __restrict__ x, const float* __restrict__ offset,
    const float* __restrict__ wt, const float* __restrict__ bias,
    float* __restrict__ out) {
    __shared__ int s_idx[4][KTAPS][64];
    __shared__ float s_bw[4][KTAPS][64];
    __shared__ float s_W[36][COUT];
    __shared__ float s_cols[36][64];

    const int tid = threadIdx.x;
    const int bx = blockIdx.x;
    const int n = bx >> 6;
    const int t_img = bx & 63;
    const int tile_y = (t_img >> 3) << 3;
    const int tile_x = (t_img & 7) << 3;

    const float* offn = offset + (size_t)n * 18 * (H * W);
    for (int e = tid; e < KTAPS * 64; e += 256) {
        int k = e >> 6, p = e & 63;
        int oy = tile_y + (p >> 3), ox = tile_x + (p & 7);
        float offy = offn[(k * 2 + 0) * (H * W) + oy * W + ox];
        float offx = offn[(k * 2 + 1) * (H * W) + oy * W + ox];
        float py = (float)(oy - 1 + (k / 3)) + offy;
        float px = (float)(ox - 1 + (k % 3)) + offx;
        float y0f = floorf(py), x0f = floorf(px);
        int y0 = (int)y0f, x0 = (int)x0f, y1 = y0 + 1, x1 = x0 + 1;
        float ly = py - y0f, lx = px - x0f, hy = 1.f - ly, hx = 1.f - lx;
        bool vy0 = (y0 >= 0) && (y0 < H), vy1 = (y1 >= 0) && (y1 < H);
        bool vx0 = (x0 >= 0) && (x0 < W), vx1 = (x1 >= 0) && (x1 < W);
        int cy0 = min(max(y0, 0), H - 1), cx0 = min(max(x0, 0), W - 1);
        int cy1 = min(max(y1, 0), H - 1), cx1 = min(max(x1, 0), W - 1);
        s_idx[0][k][p] = cy0 * W + cx0;
        s_idx[1][k][p] = cy0 * W + cx1;
        s_idx[2][k][p] = cy1 * W + cx0;
        s_idx[3][k][p] = cy1 * W + cx1;
        s_bw[0][k][p] = (vy0 && vx0) ? hy * hx : 0.f;
        s_bw[1][k][p] = (vy0 && vx1) ? hy * lx : 0.f;
        s_bw[2][k][p] = (vy1 && vx0) ? ly * hx : 0.f;
        s_bw[3][k][p] = (vy1 && vx1) ? ly * lx : 0.f;
    }

    float acc[8][8];
#pragma unroll
    for (int i = 0; i < 8; ++i)
#pragma unroll
        for (int j = 0; j < 8; ++j) acc[i][j] = 0.f;

    const int ty = tid >> 3;
    const int tx = tid & 7;
    const int q = tid >> 6;
    const int pl = tid & 63;
    const float* xn = x + (size_t)(n * CIN) * (H * W);

    for (int ch = 0; ch < CIN / 4; ++ch) {
        const int c0 = ch * 4;
        __syncthreads();
        {
            const int rbase = q * KTAPS;
            const int co4 = (tid & 63) * 4;
#pragma unroll
            for (int i = 0; i < KTAPS; ++i) {
                int r = rbase + i;
                *reinterpret_cast<float4*>(&s_W[r][co4]) =
                    *reinterpret_cast<const float4*>(&wt[(size_t)(c0 * KTAPS + r) * COUT + co4]);
            }
        }
#pragma unroll
        for (int s = 0; s < KTAPS; ++s) {
            int r = q + 4 * s;
            int c = r / 9;
            int k = r - c * 9;
            const float* xc = xn + (size_t)(c0 + c) * (H * W);
            float v = s_bw[0][k][pl] * xc[s_idx[0][k][pl]] +
                      s_bw[1][k][pl] * xc[s_idx[1][k][pl]] +
                      s_bw[2][k][pl] * xc[s_idx[2][k][pl]] +
                      s_bw[3][k][pl] * xc[s_idx[3][k][pl]];
            s_cols[r][pl] = v;
        }
        __syncthreads();
#pragma unroll 4
        for (int r = 0; r < 36; ++r) {
            const float4 cv0 = *reinterpret_cast<const float4*>(&s_cols[r][tx * 8]);
            const float4 cv1 = *reinterpret_cast<const float4*>(&s_cols[r][tx * 8 + 4]);
            const float4 wv0 = *reinterpret_cast<const float4*>(&s_W[r][ty * 8]);
            const float4 wv1 = *reinterpret_cast<const float4*>(&s_W[r][ty * 8 + 4]);
            const float wa[8] = {wv0.x, wv0.y, wv0.z, wv0.w, wv1.x, wv1.y, wv1.z, wv1.w};
            const float ca[8] = {cv0.x, cv0.y, cv0.z, cv0.w, cv1.x, cv1.y, cv1.z, cv1.w};
#pragma unroll
            for (int i = 0; i < 8; ++i)
#pragma unroll
                for (int j = 0; j < 8; ++j) acc[i][j] += wa[i] * ca[j];
        }
    }

    float* outn = out + (size_t)(n * COUT) * (H * W);
    const int obase = (tile_y + tx) * W + tile_x;
#pragma unroll
    for (int i = 0; i < 8; ++i) {
        int co = ty * 8 + i;
        float b = bias[co];
        float4 o0, o1;
        o0.x = acc[i][0] + b; o0.y = acc[i][1] + b; o0.z = acc[i][2] + b; o0.w = acc[i][3] + b;
        o1.x = acc[i][4] + b; o1.y = acc[i][5] + b; o1.z = acc[i][6] + b; o1.w = acc[i][7] + b;
        float* po = &outn[(size_t)co * (H * W) + obase];
        *reinterpret_cast<float4*>(po) = o0;
        *reinterpret_cast<float4*>(po + 4) = o1;
    }
}

extern "C" void kernel_launch(void* const* d_in, const int* in_sizes, int n_in,
                              void* d_out, int out_size, void* d_ws, size_t ws_size,
                              hipStream_t stream) {
    const float* x = (const float*)d_in[0];       // [8,256,64,64]
    const float* offset = (const float*)d_in[1];  // [8,18,64,64]
    const float* weight = (const float*)d_in[2];  // [256,256,3,3]
    const float* bias = (const float*)d_in[3];    // [256]
    float* out = (float*)d_out;

    const size_t XT_OFF = 2u * 1024 * 1024;
    const size_t need = XT_OFF + (size_t)NIMG * H * W * CIN * sizeof(f16);  // ~18.8 MB

    if (ws_size >= need) {
        f16* wt = (f16*)d_ws;                    // 1.18 MB
        f16* xt = (f16*)((char*)d_ws + XT_OFF);  // 16.8 MB
        dcn_prep<<<2048 + COUT, 256, 0, stream>>>(x, weight, xt, wt);
        dcn_mfma<<<NIMG * 64, 512, 0, stream>>>(xt, offset, wt, bias, out);
    } else {
        float* wtf = (float*)d_ws;  // fp32 fallback
        dim3 tgrid(CK / 32, COUT / 32);
        dcn_transpose_w<<<tgrid, 256, 0, stream>>>(weight, wtf);
        dcn_main<<<NIMG * 64, 256, 0, stream>>>(x, offset, wtf, bias, out);
    }
}

// Round 13
// 180.461 us; speedup vs baseline: 1.4063x; 1.4063x over previous
//
#include <hip/hip_runtime.h>

// Deformable conv2d N=8 C=256 H=W=64 Cout=256 3x3 s1 p1 d1 g1 dg1, fp32 I/O.
// fp16-MFMA implicit GEMM, v5:
//  - 256-thread/4-wave blocks (v3 skeleton), K-step=64 -> 36 iterations,
//    32 MFMA per wave per barrier (2x v3's work/barrier, 0.5x barrier count).
//  - A-frags loaded BEFORE the barrier (latency hidden by sync).
//  - Gathers for it+1 issued mid-iteration (full-iteration latency window).
//  - XCD-local images (n = bx&7, kept from v4: FETCH 24.9->18.7 MB).
//  - Vectorized sampling tables: int4 corner offsets + f16x4 weights.
//  - Prep rewritten: no-LDS register-transpose xprep + wprep in one launch.

#define H 64
#define W 64
#define CIN 256
#define COUT 256
#define NIMG 8
#define KTAPS 9
#define CK (CIN * KTAPS)  // 2304
#define NITER 36          // K-chunks of 64

typedef _Float16 f16;
typedef __attribute__((ext_vector_type(4))) _Float16 f16x4;
typedef __attribute__((ext_vector_type(8))) _Float16 f16x8;
typedef __attribute__((ext_vector_type(4))) float f32x4;

// ---------------- fused prep ----------------
// blocks 0..511   : xprep, block=(n,pb): NCHW fp32 -> NHWC fp16, reg transpose
// blocks 512..767 : wprep, one co row per block -> wt[co][tap*256+c]
__global__ __launch_bounds__(256) void dcn_prep(const float* __restrict__ x,
                                                const float* __restrict__ w,
                                                f16* __restrict__ xt,
                                                f16* __restrict__ wt) {
    const int b = blockIdx.x;
    const int t = threadIdx.x;
    if (b < 512) {
        const int n = b >> 6, pb = b & 63;
        const int q = t & 63;   // channel quad: c = q*4 .. q*4+3
        const int hg = t >> 6;  // pixel group: pixels hg*16 .. hg*16+15
        const float* xn = x + (size_t)n * CIN * (H * W) + pb * 64;
        float4 ld[4][4];  // [channel j][pixel quad pq]
#pragma unroll
        for (int j = 0; j < 4; ++j)
#pragma unroll
            for (int pq = 0; pq < 4; ++pq)
                ld[j][pq] = *(const float4*)(xn + (size_t)(q * 4 + j) * (H * W) +
                                             hg * 16 + pq * 4);
        f16* xtn = xt + (size_t)n * (H * W) * CIN + (size_t)(pb * 64 + hg * 16) * CIN + q * 4;
#pragma unroll
        for (int pq = 0; pq < 4; ++pq) {
#pragma unroll
            for (int pe = 0; pe < 4; ++pe) {
                const float* l0 = (const float*)&ld[0][pq];
                const float* l1 = (const float*)&ld[1][pq];
                const float* l2 = (const float*)&ld[2][pq];
                const float* l3 = (const float*)&ld[3][pq];
                f16x4 o = {(f16)l0[pe], (f16)l1[pe], (f16)l2[pe], (f16)l3[pe]};
                *(f16x4*)(xtn + (size_t)(pq * 4 + pe) * CIN) = o;
            }
        }
    } else {
        __shared__ f16 tw[CK];
        const int co = b - 512;
        const float* wr = w + (size_t)co * CK + t * 9;
        float v[9];
#pragma unroll
        for (int j = 0; j < 9; ++j) v[j] = wr[j];
#pragma unroll
        for (int j = 0; j < 9; ++j) tw[j * 256 + t] = (f16)v[j];  // [tap][c]
        __syncthreads();
        f16* o = wt + (size_t)co * CK;
        for (int i = t; i < CK / 8; i += 256)
            *(f16x8*)(o + i * 8) = *(const f16x8*)(tw + i * 8);
    }
}

// ---------------- main fp16-MFMA kernel ----------------
__global__ __launch_bounds__(256, 2) void dcn_mfma(
    const f16* __restrict__ xt, const float* __restrict__ offset,
    const f16* __restrict__ wt, const float* __restrict__ bias,
    float* __restrict__ out) {
    __shared__ int4 s_pix4[KTAPS][64];     // 4 corner row byte offsets   9216 B
    __shared__ f16 s_wbh4[KTAPS][64][4];   // 4 bilinear weights          4608 B
    __shared__ f16 s_cols[2][64][72];      // dbuf cols, pad 72          18432 B

    const int tid = threadIdx.x;
    const int bx = blockIdx.x;
    const int n = bx & 7;       // XCD-local image
    const int t_img = bx >> 3;  // 64 tiles of 8x8
    const int tile_y = (t_img >> 3) << 3, tile_x = (t_img & 7) << 3;

    // ---- sampling tables ----
    const float* offn = offset + (size_t)n * 18 * (H * W);
    for (int e = tid; e < KTAPS * 64; e += 256) {
        int k = e >> 6, p = e & 63;
        int oy = tile_y + (p >> 3), ox = tile_x + (p & 7);
        float offy = offn[(k * 2 + 0) * (H * W) + oy * W + ox];
        float offx = offn[(k * 2 + 1) * (H * W) + oy * W + ox];
        float py = (float)(oy - 1 + (k / 3)) + offy;
        float px = (float)(ox - 1 + (k % 3)) + offx;
        float y0f = floorf(py), x0f = floorf(px);
        int y0 = (int)y0f, x0 = (int)x0f, y1 = y0 + 1, x1 = x0 + 1;
        float ly = py - y0f, lx = px - x0f, hy = 1.f - ly, hx = 1.f - lx;
        bool vy0 = (y0 >= 0) && (y0 < H), vy1 = (y1 >= 0) && (y1 < H);
        bool vx0 = (x0 >= 0) && (x0 < W), vx1 = (x1 >= 0) && (x1 < W);
        int cy0 = min(max(y0, 0), H - 1), cx0 = min(max(x0, 0), W - 1);
        int cy1 = min(max(y1, 0), H - 1), cx1 = min(max(x1, 0), W - 1);
        s_pix4[k][p] = make_int4((cy0 * W + cx0) * (CIN * 2), (cy0 * W + cx1) * (CIN * 2),
                                 (cy1 * W + cx0) * (CIN * 2), (cy1 * W + cx1) * (CIN * 2));
        s_wbh4[k][p][0] = (f16)((vy0 && vx0) ? hy * hx : 0.f);
        s_wbh4[k][p][1] = (f16)((vy0 && vx1) ? hy * lx : 0.f);
        s_wbh4[k][p][2] = (f16)((vy1 && vx0) ? ly * hx : 0.f);
        s_wbh4[k][p][3] = (f16)((vy1 && vx1) ? ly * lx : 0.f);
    }

    f32x4 acc[4][4];
#pragma unroll
    for (int i = 0; i < 4; ++i)
#pragma unroll
        for (int j = 0; j < 4; ++j) acc[i][j] = (f32x4)0.f;

    const int lane = tid & 63, wv = tid >> 6;
    const int co_base = wv * 64;
    // gather staging: thread -> (pixel p_g, 16-channel slot qk)
    const int p_g = tid >> 2;
    const int qk = tid & 3;
    const char* xb = (const char*)(xt + (size_t)n * (H * W) * CIN);

    // A-row pointers (k0 = it*64 linear)
    const f16* arow[4];
#pragma unroll
    for (int cf = 0; cf < 4; ++cf)
        arow[cf] = wt + (size_t)(co_base + 16 * cf + (lane & 15)) * CK + (lane >> 4) * 8;

    __syncthreads();  // tables ready

    // ---- prologue: issue gathers for it=0 (tap 0, cb 0) ----
    f16x8 hb[8];
    {
        int4 cp = s_pix4[0][p_g];
        const char* b0 = xb + qk * 32;
        hb[0] = *(const f16x8*)(b0 + cp.x);
        hb[1] = *(const f16x8*)(b0 + cp.x + 16);
        hb[2] = *(const f16x8*)(b0 + cp.y);
        hb[3] = *(const f16x8*)(b0 + cp.y + 16);
        hb[4] = *(const f16x8*)(b0 + cp.z);
        hb[5] = *(const f16x8*)(b0 + cp.z + 16);
        hb[6] = *(const f16x8*)(b0 + cp.w);
        hb[7] = *(const f16x8*)(b0 + cp.w + 16);
    }

    // ---- main loop: 36 iterations, ONE barrier each ----
    for (int it = 0; it < NITER; ++it) {
        const int cur = it & 1;
        const int tap = it >> 2;
        // 1. combine this iteration's gathers -> cols buf[cur]
        {
            f16x4 wb = *(const f16x4*)&s_wbh4[tap][p_g][0];
            f16x8 v0 = hb[0] * wb[0] + hb[2] * wb[1] + hb[4] * wb[2] + hb[6] * wb[3];
            f16x8 v1 = hb[1] * wb[0] + hb[3] * wb[1] + hb[5] * wb[2] + hb[7] * wb[3];
            *(f16x8*)&s_cols[cur][p_g][qk * 16] = v0;
            *(f16x8*)&s_cols[cur][p_g][qk * 16 + 8] = v1;
        }
        // 2. issue gathers for it+1 (land during next iteration's front)
        if (it + 1 < NITER) {
            const int t1 = (it + 1) >> 2;
            int4 cp = s_pix4[t1][p_g];
            const char* b0 = xb + ((it + 1) & 3) * 128 + qk * 32;
            hb[0] = *(const f16x8*)(b0 + cp.x);
            hb[1] = *(const f16x8*)(b0 + cp.x + 16);
            hb[2] = *(const f16x8*)(b0 + cp.y);
            hb[3] = *(const f16x8*)(b0 + cp.y + 16);
            hb[4] = *(const f16x8*)(b0 + cp.z);
            hb[5] = *(const f16x8*)(b0 + cp.z + 16);
            hb[6] = *(const f16x8*)(b0 + cp.w);
            hb[7] = *(const f16x8*)(b0 + cp.w + 16);
        }
        // 3. A-frags for this iteration (global, issued before barrier)
        f16x8 af[8];
        {
            const int k0 = it * 64;
#pragma unroll
            for (int cf = 0; cf < 4; ++cf) {
                af[cf] = *(const f16x8*)(arow[cf] + k0);
                af[4 + cf] = *(const f16x8*)(arow[cf] + k0 + 32);
            }
        }
        // 4. barrier: cols[cur] visible (writes above, reads below)
        __syncthreads();
        // 5. MFMA: 2 k-subs x (4 co x 4 p) = 32 MFMA
#pragma unroll
        for (int ks = 0; ks < 2; ++ks) {
            f16x8 bf[4];
#pragma unroll
            for (int pf = 0; pf < 4; ++pf)
                bf[pf] = *(const f16x8*)&s_cols[cur][16 * pf + (lane & 15)]
                                               [ks * 32 + (lane >> 4) * 8];
#pragma unroll
            for (int cf = 0; cf < 4; ++cf)
#pragma unroll
                for (int pf = 0; pf < 4; ++pf)
                    acc[cf][pf] = __builtin_amdgcn_mfma_f32_16x16x32_f16(
                        af[ks * 4 + cf], bf[pf], acc[cf][pf], 0, 0, 0);
        }
    }

    // ---- epilogue (verified v3 mapping): col=lane&15 (p), row=(lane>>4)*4+r (co) ----
    float* outn = out + (size_t)n * COUT * (H * W);
#pragma unroll
    for (int cf = 0; cf < 4; ++cf) {
#pragma unroll
        for (int r = 0; r < 4; ++r) {
            int co = co_base + 16 * cf + ((lane >> 4) << 2) + r;
            float b = bias[co];
#pragma unroll
            for (int pf = 0; pf < 4; ++pf) {
                int pp = 16 * pf + (lane & 15);
                int oy = tile_y + (pp >> 3), ox = tile_x + (pp & 7);
                outn[(size_t)co * (H * W) + oy * W + ox] = acc[cf][pf][r] + b;
            }
        }
    }
}

// ---------------- fallback fp32 path (ws too small) ----------------
__global__ __launch_bounds__(256) void dcn_transpose_w(const float* __restrict__ w,
                                                       float* __restrict__ wt) {
    __shared__ float tile[32][33];
    const int ckb = blockIdx.x * 32;
    const int cob = blockIdx.y * 32;
    const int tx = threadIdx.x & 31;
    const int ty = threadIdx.x >> 5;
#pragma unroll
    for (int i = 0; i < 32; i += 8)
        tile[ty + i][tx] = w[(size_t)(cob + ty + i) * CK + ckb + tx];
    __syncthreads();
#pragma unroll
    for (int i = 0; i < 32; i += 8)
        wt[(size_t)(ckb + ty + i) * COUT + cob + tx] = tile[tx][ty + i];
}

__global__ __launch_bounds__(256, 2) void dcn_main(
    const float* __restrict__ x, const float* __restrict__ offset,
    const float* __restrict__ wt, const float* __restrict__ bias,
    float* __restrict__ out) {
    __shared__ int s_idx[4][KTAPS][64];
    __shared__ float s_bw[4][KTAPS][64];
    __shared__ float s_W[36][COUT];
    __shared__ float s_cols[36][64];

    const int tid = threadIdx.x;
    const int bx = blockIdx.x;
    const int n = bx >> 6;
    const int t_img = bx & 63;
    const int tile_y = (t_img >> 3) << 3;
    const int tile_x = (t_img & 7) << 3;

    const float* offn = offset + (size_t)n * 18 * (H * W);
    for (int e = tid; e < KTAPS * 64; e += 256) {
        int k = e >> 6, p = e & 63;
        int oy = tile_y + (p >> 3), ox = tile_x + (p & 7);
        float offy = offn[(k * 2 + 0) * (H * W) + oy * W + ox];
        float offx = offn[(k * 2 + 1) * (H * W) + oy * W + ox];
        float py = (float)(oy - 1 + (k / 3)) + offy;
        float px = (float)(ox - 1 + (k % 3)) + offx;
        float y0f = floorf(py), x0f = floorf(px);
        int y0 = (int)y0f, x0 = (int)x0f, y1 = y0 + 1, x1 = x0 + 1;
        float ly = py - y0f, lx = px - x0f, hy = 1.f - ly, hx = 1.f - lx;
        bool vy0 = (y0 >= 0) && (y0 < H), vy1 = (y1 >= 0) && (y1 < H);
        bool vx0 = (x0 >= 0) && (x0 < W), vx1 = (x1 >= 0) && (x1 < W);
        int cy0 = min(max(y0, 0), H - 1), cx0 = min(max(x0, 0), W - 1);
        int cy1 = min(max(y1, 0), H - 1), cx1 = min(max(x1, 0), W - 1);
        s_idx[0][k][p] = cy0 * W + cx0;
        s_idx[1][k][p] = cy0 * W + cx1;
        s_idx[2][k][p] = cy1 * W + cx0;
        s_idx[3][k][p] = cy1 * W + cx1;
        s_bw[0][k][p] = (vy0 && vx0) ? hy * hx : 0.f;
        s_bw[1][k][p] = (vy0 && vx1) ? hy * lx : 0.f;
        s_bw[2][k][p] = (vy1 && vx0) ? ly * hx : 0.f;
        s_bw[3][k][p] = (vy1 && vx1) ? ly * lx : 0.f;
    }

    float acc[8][8];
#pragma unroll
    for (int i = 0; i < 8; ++i)
#pragma unroll
        for (int j = 0; j < 8; ++j) acc[i][j] = 0.f;

    const int ty = tid >> 3;
    const int tx = tid & 7;
    const int q = tid >> 6;
    const int pl = tid & 63;
    const float* xn = x + (size_t)(n * CIN) * (H * W);

    for (int ch = 0; ch < CIN / 4; ++ch) {
        const int c0 = ch * 4;
        __syncthreads();
        {
            const int rbase = q * KTAPS;
            const int co4 = (tid & 63) * 4;
#pragma unroll
            for (int i = 0; i < KTAPS; ++i) {
                int r = rbase + i;
                *reinterpret_cast<float4*>(&s_W[r][co4]) =
                    *reinterpret_cast<const float4*>(&wt[(size_t)(c0 * KTAPS + r) * COUT + co4]);
            }
        }
#pragma unroll
        for (int s = 0; s < KTAPS; ++s) {
            int r = q + 4 * s;
            int c = r / 9;
            int k = r - c * 9;
            const float* xc = xn + (size_t)(c0 + c) * (H * W);
            float v = s_bw[0][k][pl] * xc[s_idx[0][k][pl]] +
                      s_bw[1][k][pl] * xc[s_idx[1][k][pl]] +
                      s_bw[2][k][pl] * xc[s_idx[2][k][pl]] +
                      s_bw[3][k][pl] * xc[s_idx[3][k][pl]];
            s_cols[r][pl] = v;
        }
        __syncthreads();
#pragma unroll 4
        for (int r = 0; r < 36; ++r) {
            const float4 cv0 = *reinterpret_cast<const float4*>(&s_cols[r][tx * 8]);
            const float4 cv1 = *reinterpret_cast<const float4*>(&s_cols[r][tx * 8 + 4]);
            const float4 wv0 = *reinterpret_cast<const float4*>(&s_W[r][ty * 8]);
            const float4 wv1 = *reinterpret_cast<const float4*>(&s_W[r][ty * 8 + 4]);
            const float wa[8] = {wv0.x, wv0.y, wv0.z, wv0.w, wv1.x, wv1.y, wv1.z, wv1.w};
            const float ca[8] = {cv0.x, cv0.y, cv0.z, cv0.w, cv1.x, cv1.y, cv1.z, cv1.w};
#pragma unroll
            for (int i = 0; i < 8; ++i)
#pragma unroll
                for (int j = 0; j < 8; ++j) acc[i][j] += wa[i] * ca[j];
        }
    }

    float* outn = out + (size_t)(n * COUT) * (H * W);
    const int obase = (tile_y + tx) * W + tile_x;
#pragma unroll
    for (int i = 0; i < 8; ++i) {
        int co = ty * 8 + i;
        float b = bias[co];
        float4 o0, o1;
        o0.x = acc[i][0] + b; o0.y = acc[i][1] + b; o0.z = acc[i][2] + b; o0.w = acc[i][3] + b;
        o1.x = acc[i][4] + b; o1.y = acc[i][5] + b; o1.z = acc[i][6] + b; o1.w = acc[i][7] + b;
        float* po = &outn[(size_t)co * (H * W) + obase];
        *reinterpret_cast<float4*>(po) = o0;
        *reinterpret_cast<float4*>(po + 4) = o1;
    }
}

extern "C" void kernel_launch(void* const* d_in, const int* in_sizes, int n_in,
                              void* d_out, int out_size, void* d_ws, size_t ws_size,
                              hipStream_t stream) {
    const float* x = (const float*)d_in[0];       // [8,256,64,64]
    const float* offset = (const float*)d_in[1];  // [8,18,64,64]
    const float* weight = (const float*)d_in[2];  // [256,256,3,3]
    const float* bias = (const float*)d_in[3];    // [256]
    float* out = (float*)d_out;

    const size_t XT_OFF = 2u * 1024 * 1024;
    const size_t need = XT_OFF + (size_t)NIMG * H * W * CIN * sizeof(f16);  // ~18.8 MB

    if (ws_size >= need) {
        f16* wt = (f16*)d_ws;                    // 1.18 MB
        f16* xt = (f16*)((char*)d_ws + XT_OFF);  // 16.8 MB
        dcn_prep<<<512 + COUT, 256, 0, stream>>>(x, weight, xt, wt);
        dcn_mfma<<<NIMG * 64, 256, 0, stream>>>(xt, offset, wt, bias, out);
    } else {
        float* wtf = (float*)d_ws;  // fp32 fallback
        dim3 tgrid(CK / 32, COUT / 32);
        dcn_transpose_w<<<tgrid, 256, 0, stream>>>(weight, wtf);
        dcn_main<<<NIMG * 64, 256, 0, stream>>>(x, offset, wtf, bias, out);
    }
}